// Round 2
// baseline (1197.435 us; speedup 1.0000x reference)
//
#include <hip/hip_runtime.h>
#include <hip/hip_bf16.h>

#define N_NODES 50000
#define DIM 256
#define N_EDGES 1600000
#define NBUK 196          // buckets of 256 nodes: 196*256 = 50176 >= 50000

typedef float f32x4 __attribute__((ext_vector_type(4)));
typedef __bf16 bf16x8 __attribute__((ext_vector_type(8)));
typedef __bf16 bf16x4 __attribute__((ext_vector_type(4)));

// ---------------- W -> bf16 ----------------
__global__ void convw_k(const float* __restrict__ W, __bf16* __restrict__ Wbf) {
    int i = blockIdx.x * blockDim.x + threadIdx.x;
    if (i < DIM * DIM) Wbf[i] = (__bf16)W[i];
}

// ---------------- Y = feature @ W.T  (bf16 MFMA, no LDS) ----------------
__global__ __launch_bounds__(256) void gemm_y(const float* __restrict__ feat,
                                              const __bf16* __restrict__ Wbf,
                                              __bf16* __restrict__ Ybf) {
    const int wid  = threadIdx.x >> 6;
    const int lane = threadIdx.x & 63;
    const int row0 = blockIdx.x * 64 + wid * 16;
    const int mrow = lane & 15;
    const int kgrp = lane >> 4;          // 0..3

    int arow = row0 + mrow;
    int arow_c = arow < N_NODES ? arow : (N_NODES - 1);
    const float* aptr = feat + (size_t)arow_c * DIM + kgrp * 8;

    f32x4 acc[16];
#pragma unroll
    for (int i = 0; i < 16; ++i) acc[i] = (f32x4)0.0f;

#pragma unroll
    for (int ks = 0; ks < 8; ++ks) {
        const float* ap = aptr + ks * 32;
        f32x4 a0 = *(const f32x4*)(ap);
        f32x4 a1 = *(const f32x4*)(ap + 4);
        bf16x8 af;
        af[0] = (__bf16)a0[0]; af[1] = (__bf16)a0[1];
        af[2] = (__bf16)a0[2]; af[3] = (__bf16)a0[3];
        af[4] = (__bf16)a1[0]; af[5] = (__bf16)a1[1];
        af[6] = (__bf16)a1[2]; af[7] = (__bf16)a1[3];
#pragma unroll
        for (int nt = 0; nt < 16; ++nt) {
            int ncol = nt * 16 + mrow;   // B col for this lane
            const bf16x8 bf = *(const bf16x8*)(Wbf + (size_t)ncol * DIM + ks * 32 + kgrp * 8);
            acc[nt] = __builtin_amdgcn_mfma_f32_16x16x32_bf16(af, bf, acc[nt], 0, 0, 0);
        }
    }

    // C/D layout (m89): col = lane&15, row = (lane>>4)*4 + reg
    int crow_base = row0 + kgrp * 4;
#pragma unroll
    for (int r = 0; r < 4; ++r) {
        int crow = crow_base + r;
        if (crow < N_NODES) {
            __bf16* yp = Ybf + (size_t)crow * DIM + mrow;
#pragma unroll
            for (int nt = 0; nt < 16; ++nt)
                yp[nt * 16] = (__bf16)acc[nt][r];
        }
    }
}

// ---------------- degree histogram ----------------
__global__ void hist_k(const int* __restrict__ dst, int* __restrict__ deg) {
    int e = blockIdx.x * blockDim.x + threadIdx.x;
    if (e < N_EDGES) atomicAdd(&deg[dst[e]], 1);
}

// ---------------- scan phase A: per-block (=per-bucket) degree sums ----------------
__global__ __launch_bounds__(256) void scanA_k(const int* __restrict__ deg,
                                               int* __restrict__ bsum) {
    __shared__ int sm[256];
    int t = threadIdx.x;
    int idx = blockIdx.x * 256 + t;
    int v = (idx < N_NODES) ? deg[idx] : 0;
    sm[t] = v;
    __syncthreads();
    for (int off = 128; off > 0; off >>= 1) {
        if (t < off) sm[t] += sm[t + off];
        __syncthreads();
    }
    if (t == 0) bsum[blockIdx.x] = sm[0];
}

// ---------------- scan phase B: exclusive scan of 196 bucket sums ----------------
__global__ __launch_bounds__(256) void scanB_k(const int* __restrict__ bsum,
                                               int* __restrict__ bbase,
                                               int* __restrict__ bcur,
                                               int* __restrict__ offsets) {
    __shared__ int sm[256];
    int t = threadIdx.x;
    int v = (t < NBUK) ? bsum[t] : 0;
    sm[t] = v;
    __syncthreads();
    for (int off = 1; off < 256; off <<= 1) {
        int x = (t >= off) ? sm[t - off] : 0;
        __syncthreads();
        sm[t] += x;
        __syncthreads();
    }
    int excl = sm[t] - v;
    if (t < NBUK) { bbase[t] = excl; bcur[t] = excl; }
    if (t == 0) offsets[N_NODES] = N_EDGES;
}

// ---------------- scan phase C: per-node exclusive offsets ----------------
__global__ __launch_bounds__(256) void scanC_k(const int* __restrict__ deg,
                                               const int* __restrict__ bbase,
                                               int* __restrict__ offsets,
                                               int* __restrict__ cursor) {
    __shared__ int sm[256];
    int t = threadIdx.x;
    int idx = blockIdx.x * 256 + t;
    int v = (idx < N_NODES) ? deg[idx] : 0;
    sm[t] = v;
    __syncthreads();
    for (int off = 1; off < 256; off <<= 1) {
        int x = (t >= off) ? sm[t - off] : 0;
        __syncthreads();
        sm[t] += x;
        __syncthreads();
    }
    int excl = sm[t] - v + bbase[blockIdx.x];
    if (idx < N_NODES) { offsets[idx] = excl; cursor[idx] = excl; }
}

// ---------------- binned append: stage (dst_local, src) per bucket ----------------
__global__ void append_k(const int* __restrict__ src, const int* __restrict__ dst,
                         int* __restrict__ bcur, unsigned int* __restrict__ stage) {
    int e = blockIdx.x * blockDim.x + threadIdx.x;
    if (e < N_EDGES) {
        int d = dst[e];
        int s = src[e];            // < 50000 -> fits in 16 bits
        int b = d >> 8;
        int pos = atomicAdd(&bcur[b], 1);
        stage[pos] = (unsigned int)s | ((unsigned int)(d & 255) << 16);
    }
}

// ---------------- per-bucket finalize: CSR edge_src (writes confined to ~32KB) ---
__global__ __launch_bounds__(256) void finalize_k(const unsigned int* __restrict__ stage,
                                                  const int* __restrict__ bbase,
                                                  const int* __restrict__ bcur,
                                                  int* __restrict__ cursor,
                                                  int* __restrict__ edge_src) {
    int b = blockIdx.x;
    int beg = bbase[b];
    int end = bcur[b];             // post-append cursor = beg + count
    int dbase = b << 8;
    for (int i = beg + threadIdx.x; i < end; i += 256) {
        unsigned int u = stage[i];
        int s = (int)(u & 0xFFFFu);
        int d = dbase | (int)(u >> 16);
        int pos = atomicAdd(&cursor[d], 1);
        edge_src[pos] = s;
    }
}

// ---------------- per-node gather-mean + bias ----------------
__global__ __launch_bounds__(256) void aggregate_k(const __bf16* __restrict__ Ybf,
                                                   const int* __restrict__ offsets,
                                                   const int* __restrict__ edge_src,
                                                   const float* __restrict__ bias,
                                                   float* __restrict__ out) {
    int node = blockIdx.x * 4 + (threadIdx.x >> 6);
    if (node >= N_NODES) return;
    int lane = threadIdx.x & 63;
    int c0 = lane * 4;

    int beg = offsets[node];
    int end = offsets[node + 1];
    float a0 = 0.f, a1 = 0.f, a2 = 0.f, a3 = 0.f;

    int j = beg;
    for (; j + 1 < end; j += 2) {
        int s0 = edge_src[j];
        int s1 = edge_src[j + 1];
        bf16x4 v0 = *(const bf16x4*)(Ybf + (size_t)s0 * DIM + c0);
        bf16x4 v1 = *(const bf16x4*)(Ybf + (size_t)s1 * DIM + c0);
        a0 += (float)v0[0] + (float)v1[0];
        a1 += (float)v0[1] + (float)v1[1];
        a2 += (float)v0[2] + (float)v1[2];
        a3 += (float)v0[3] + (float)v1[3];
    }
    if (j < end) {
        int s0 = edge_src[j];
        bf16x4 v0 = *(const bf16x4*)(Ybf + (size_t)s0 * DIM + c0);
        a0 += (float)v0[0];
        a1 += (float)v0[1];
        a2 += (float)v0[2];
        a3 += (float)v0[3];
    }

    int deg = end - beg;
    f32x4 bv = *(const f32x4*)(bias + c0);
    f32x4 r;
    if (deg > 0) {
        float inv = 1.0f / (float)deg;
        r[0] = a0 * inv + bv[0];
        r[1] = a1 * inv + bv[1];
        r[2] = a2 * inv + bv[2];
        r[3] = a3 * inv + bv[3];
    } else {
        bf16x4 v = *(const bf16x4*)(Ybf + (size_t)node * DIM + c0);
        r[0] = (float)v[0] + bv[0];
        r[1] = (float)v[1] + bv[1];
        r[2] = (float)v[2] + bv[2];
        r[3] = (float)v[3] + bv[3];
    }
    *(f32x4*)(out + (size_t)node * DIM + c0) = r;
}

static inline size_t align64(size_t x) { return (x + 63) & ~(size_t)63; }

extern "C" void kernel_launch(void* const* d_in, const int* in_sizes, int n_in,
                              void* d_out, int out_size, void* d_ws, size_t ws_size,
                              hipStream_t stream) {
    const float* feature = (const float*)d_in[0];
    const int*   src     = (const int*)d_in[1];
    const int*   dst     = (const int*)d_in[2];
    const float* W       = (const float*)d_in[3];
    const float* b       = (const float*)d_in[4];
    float* out = (float*)d_out;

    // workspace layout (~39.2 MB total)
    char* ws = (char*)d_ws;
    __bf16* Ybf = (__bf16*)ws;              ws += align64((size_t)N_NODES * DIM * 2);
    __bf16* Wbf = (__bf16*)ws;              ws += align64((size_t)DIM * DIM * 2);
    int* deg      = (int*)ws;               ws += align64((size_t)N_NODES * 4);
    int* offsets  = (int*)ws;               ws += align64((size_t)(N_NODES + 1) * 4);
    int* cursor   = (int*)ws;               ws += align64((size_t)N_NODES * 4);
    int* bsum     = (int*)ws;               ws += align64((size_t)NBUK * 4);
    int* bbase    = (int*)ws;               ws += align64((size_t)NBUK * 4);
    int* bcur     = (int*)ws;               ws += align64((size_t)NBUK * 4);
    unsigned int* stage = (unsigned int*)ws; ws += align64((size_t)N_EDGES * 4);
    int* edge_src = (int*)ws;               ws += align64((size_t)N_EDGES * 4);

    hipMemsetAsync(deg, 0, (size_t)N_NODES * 4, stream);

    convw_k<<<(DIM * DIM + 255) / 256, 256, 0, stream>>>(W, Wbf);
    gemm_y<<<(N_NODES + 63) / 64, 256, 0, stream>>>(feature, Wbf, Ybf);
    hist_k<<<(N_EDGES + 255) / 256, 256, 0, stream>>>(dst, deg);
    scanA_k<<<NBUK, 256, 0, stream>>>(deg, bsum);
    scanB_k<<<1, 256, 0, stream>>>(bsum, bbase, bcur, offsets);
    scanC_k<<<NBUK, 256, 0, stream>>>(deg, bbase, offsets, cursor);
    append_k<<<(N_EDGES + 255) / 256, 256, 0, stream>>>(src, dst, bcur, stage);
    finalize_k<<<NBUK, 256, 0, stream>>>(stage, bbase, bcur, cursor, edge_src);
    aggregate_k<<<(N_NODES + 3) / 4, 256, 0, stream>>>(Ybf, offsets, edge_src, b, out);
}

// Round 3
// 248.511 us; speedup vs baseline: 4.8184x; 4.8184x over previous
//
#include <hip/hip_runtime.h>
#include <hip/hip_bf16.h>

#define N_NODES 50000
#define DIM 256
#define N_EDGES 1600000
#define NBUK 196            // buckets of 256 nodes: 196*256 = 50176 >= 50000
#define CHUNK_E 4096        // edges per binning block
#define NBLK ((N_EDGES + CHUNK_E - 1) / CHUNK_E)   // 391

typedef float f32x4 __attribute__((ext_vector_type(4)));
typedef __bf16 bf16x8 __attribute__((ext_vector_type(8)));
typedef __bf16 bf16x4 __attribute__((ext_vector_type(4)));

// ---------------- W -> bf16 ----------------
__global__ void convw_k(const float* __restrict__ W, __bf16* __restrict__ Wbf) {
    int i = blockIdx.x * blockDim.x + threadIdx.x;
    if (i < DIM * DIM) Wbf[i] = (__bf16)W[i];
}

// ---------------- Y = feature @ W.T  (bf16 MFMA, no LDS) ----------------
__global__ __launch_bounds__(256) void gemm_y(const float* __restrict__ feat,
                                              const __bf16* __restrict__ Wbf,
                                              __bf16* __restrict__ Ybf) {
    const int wid  = threadIdx.x >> 6;
    const int lane = threadIdx.x & 63;
    const int row0 = blockIdx.x * 64 + wid * 16;
    const int mrow = lane & 15;
    const int kgrp = lane >> 4;          // 0..3

    int arow = row0 + mrow;
    int arow_c = arow < N_NODES ? arow : (N_NODES - 1);
    const float* aptr = feat + (size_t)arow_c * DIM + kgrp * 8;

    f32x4 acc[16];
#pragma unroll
    for (int i = 0; i < 16; ++i) acc[i] = (f32x4)0.0f;

#pragma unroll
    for (int ks = 0; ks < 8; ++ks) {
        const float* ap = aptr + ks * 32;
        f32x4 a0 = *(const f32x4*)(ap);
        f32x4 a1 = *(const f32x4*)(ap + 4);
        bf16x8 af;
        af[0] = (__bf16)a0[0]; af[1] = (__bf16)a0[1];
        af[2] = (__bf16)a0[2]; af[3] = (__bf16)a0[3];
        af[4] = (__bf16)a1[0]; af[5] = (__bf16)a1[1];
        af[6] = (__bf16)a1[2]; af[7] = (__bf16)a1[3];
#pragma unroll
        for (int nt = 0; nt < 16; ++nt) {
            int ncol = nt * 16 + mrow;   // B col for this lane
            const bf16x8 bf = *(const bf16x8*)(Wbf + (size_t)ncol * DIM + ks * 32 + kgrp * 8);
            acc[nt] = __builtin_amdgcn_mfma_f32_16x16x32_bf16(af, bf, acc[nt], 0, 0, 0);
        }
    }

    // C/D layout (m89): col = lane&15, row = (lane>>4)*4 + reg
    int crow_base = row0 + kgrp * 4;
#pragma unroll
    for (int r = 0; r < 4; ++r) {
        int crow = crow_base + r;
        if (crow < N_NODES) {
            __bf16* yp = Ybf + (size_t)crow * DIM + mrow;
#pragma unroll
            for (int nt = 0; nt < 16; ++nt)
                yp[nt * 16] = (__bf16)acc[nt][r];
        }
    }
}

// ---------------- bucket counts: per-block LDS hist, then aggregated atomics ----
__global__ __launch_bounds__(256) void count_k(const int* __restrict__ dst,
                                               int* __restrict__ gbkt) {
    __shared__ int lh[NBUK];
    for (int i = threadIdx.x; i < NBUK; i += 256) lh[i] = 0;
    __syncthreads();
    int base = blockIdx.x * CHUNK_E;
    int end = base + CHUNK_E; if (end > N_EDGES) end = N_EDGES;
    for (int e = base + threadIdx.x; e < end; e += 256)
        atomicAdd(&lh[dst[e] >> 8], 1);
    __syncthreads();
    for (int i = threadIdx.x; i < NBUK; i += 256)
        if (lh[i]) atomicAdd(&gbkt[i], lh[i]);
}

// ---------------- exclusive scan of 196 bucket totals ----------------
__global__ __launch_bounds__(256) void scanB_k(const int* __restrict__ gbkt,
                                               int* __restrict__ bbase,
                                               int* __restrict__ bcur,
                                               int* __restrict__ offsets) {
    __shared__ int sm[256];
    int t = threadIdx.x;
    int v = (t < NBUK) ? gbkt[t] : 0;
    sm[t] = v;
    __syncthreads();
    for (int off = 1; off < 256; off <<= 1) {
        int x = (t >= off) ? sm[t - off] : 0;
        __syncthreads();
        sm[t] += x;
        __syncthreads();
    }
    int excl = sm[t] - v;
    if (t < NBUK) { bbase[t] = excl; bcur[t] = excl; }
    if (t == 0) offsets[N_NODES] = N_EDGES;
}

// ---------------- place edges into bucket regions (block-local binning) --------
__global__ __launch_bounds__(256) void place_k(const int* __restrict__ src,
                                               const int* __restrict__ dst,
                                               int* __restrict__ bcur,
                                               unsigned int* __restrict__ staged) {
    __shared__ int lh[NBUK];
    __shared__ int lbase[NBUK];
    for (int i = threadIdx.x; i < NBUK; i += 256) lh[i] = 0;
    __syncthreads();
    int base = blockIdx.x * CHUNK_E;
    int end = base + CHUNK_E; if (end > N_EDGES) end = N_EDGES;
    for (int e = base + threadIdx.x; e < end; e += 256)
        atomicAdd(&lh[dst[e] >> 8], 1);
    __syncthreads();
    for (int i = threadIdx.x; i < NBUK; i += 256) {
        int c = lh[i];
        lbase[i] = c ? atomicAdd(&bcur[i], c) : 0;
        lh[i] = 0;                 // reuse as local cursor
    }
    __syncthreads();
    for (int e = base + threadIdx.x; e < end; e += 256) {
        int d = dst[e];
        int s = src[e];            // < 50000 -> fits in 16 bits
        int b = d >> 8;
        int p = atomicAdd(&lh[b], 1);
        staged[lbase[b] + p] = (unsigned int)s | ((unsigned int)(d & 255) << 16);
    }
}

// ---------------- per-bucket finalize: node offsets + CSR edge_src ----------------
__global__ __launch_bounds__(256) void finalize_k(const unsigned int* __restrict__ staged,
                                                  const int* __restrict__ bbase,
                                                  const int* __restrict__ gbkt,
                                                  int* __restrict__ offsets,
                                                  int* __restrict__ edge_src) {
    __shared__ int nh[256];
    __shared__ int nbase[256];
    __shared__ int sm[256];
    int t = threadIdx.x, b = blockIdx.x;
    int beg = bbase[b];
    int cnt = gbkt[b];
    nh[t] = 0;
    __syncthreads();
    for (int i = t; i < cnt; i += 256)
        atomicAdd(&nh[staged[beg + i] >> 16], 1);
    __syncthreads();
    int v = nh[t];
    sm[t] = v;
    __syncthreads();
    for (int off = 1; off < 256; off <<= 1) {
        int x = (t >= off) ? sm[t - off] : 0;
        __syncthreads();
        sm[t] += x;
        __syncthreads();
    }
    nbase[t] = sm[t] - v;
    int node = (b << 8) + t;
    if (node < N_NODES) offsets[node] = beg + nbase[t];
    nh[t] = 0;                     // reuse as per-node cursor
    __syncthreads();
    for (int i = t; i < cnt; i += 256) {
        unsigned int u = staged[beg + i];
        int dl = (int)(u >> 16);
        int p = atomicAdd(&nh[dl], 1);
        edge_src[beg + nbase[dl] + p] = (int)(u & 0xFFFFu);
    }
}

// ---------------- per-node gather-mean + bias ----------------
__global__ __launch_bounds__(256) void aggregate_k(const __bf16* __restrict__ Ybf,
                                                   const int* __restrict__ offsets,
                                                   const int* __restrict__ edge_src,
                                                   const float* __restrict__ bias,
                                                   float* __restrict__ out) {
    int node = blockIdx.x * 4 + (threadIdx.x >> 6);
    if (node >= N_NODES) return;
    int lane = threadIdx.x & 63;
    int c0 = lane * 4;

    int beg = offsets[node];
    int end = offsets[node + 1];
    float a0 = 0.f, a1 = 0.f, a2 = 0.f, a3 = 0.f;

    int j = beg;
    for (; j + 1 < end; j += 2) {
        int s0 = edge_src[j];
        int s1 = edge_src[j + 1];
        bf16x4 v0 = *(const bf16x4*)(Ybf + (size_t)s0 * DIM + c0);
        bf16x4 v1 = *(const bf16x4*)(Ybf + (size_t)s1 * DIM + c0);
        a0 += (float)v0[0] + (float)v1[0];
        a1 += (float)v0[1] + (float)v1[1];
        a2 += (float)v0[2] + (float)v1[2];
        a3 += (float)v0[3] + (float)v1[3];
    }
    if (j < end) {
        int s0 = edge_src[j];
        bf16x4 v0 = *(const bf16x4*)(Ybf + (size_t)s0 * DIM + c0);
        a0 += (float)v0[0];
        a1 += (float)v0[1];
        a2 += (float)v0[2];
        a3 += (float)v0[3];
    }

    int deg = end - beg;
    f32x4 bv = *(const f32x4*)(bias + c0);
    f32x4 r;
    if (deg > 0) {
        float inv = 1.0f / (float)deg;
        r[0] = a0 * inv + bv[0];
        r[1] = a1 * inv + bv[1];
        r[2] = a2 * inv + bv[2];
        r[3] = a3 * inv + bv[3];
    } else {
        bf16x4 v = *(const bf16x4*)(Ybf + (size_t)node * DIM + c0);
        r[0] = (float)v[0] + bv[0];
        r[1] = (float)v[1] + bv[1];
        r[2] = (float)v[2] + bv[2];
        r[3] = (float)v[3] + bv[3];
    }
    *(f32x4*)(out + (size_t)node * DIM + c0) = r;
}

static inline size_t align64(size_t x) { return (x + 63) & ~(size_t)63; }

extern "C" void kernel_launch(void* const* d_in, const int* in_sizes, int n_in,
                              void* d_out, int out_size, void* d_ws, size_t ws_size,
                              hipStream_t stream) {
    const float* feature = (const float*)d_in[0];
    const int*   src     = (const int*)d_in[1];
    const int*   dst     = (const int*)d_in[2];
    const float* W       = (const float*)d_in[3];
    const float* b       = (const float*)d_in[4];
    float* out = (float*)d_out;

    // workspace layout (~38.8 MB total)
    char* ws = (char*)d_ws;
    __bf16* Ybf = (__bf16*)ws;               ws += align64((size_t)N_NODES * DIM * 2);
    __bf16* Wbf = (__bf16*)ws;               ws += align64((size_t)DIM * DIM * 2);
    int* offsets  = (int*)ws;                ws += align64((size_t)(N_NODES + 1) * 4);
    int* gbkt     = (int*)ws;                ws += align64((size_t)NBUK * 4);
    int* bbase    = (int*)ws;                ws += align64((size_t)NBUK * 4);
    int* bcur     = (int*)ws;                ws += align64((size_t)NBUK * 4);
    unsigned int* staged = (unsigned int*)ws; ws += align64((size_t)N_EDGES * 4);
    int* edge_src = (int*)ws;                ws += align64((size_t)N_EDGES * 4);

    hipMemsetAsync(gbkt, 0, (size_t)NBUK * 4, stream);

    convw_k<<<(DIM * DIM + 255) / 256, 256, 0, stream>>>(W, Wbf);
    gemm_y<<<(N_NODES + 63) / 64, 256, 0, stream>>>(feature, Wbf, Ybf);
    count_k<<<NBLK, 256, 0, stream>>>(dst, gbkt);
    scanB_k<<<1, 256, 0, stream>>>(gbkt, bbase, bcur, offsets);
    place_k<<<NBLK, 256, 0, stream>>>(src, dst, bcur, staged);
    finalize_k<<<NBUK, 256, 0, stream>>>(staged, bbase, gbkt, offsets, edge_src);
    aggregate_k<<<(N_NODES + 3) / 4, 256, 0, stream>>>(Ybf, offsets, edge_src, b, out);
}